// Round 7
// baseline (616.825 us; speedup 1.0000x reference)
//
#include <hip/hip_runtime.h>
#include <math.h>

#define NN 30000
#define NE 480000

typedef _Float16 f16x8 __attribute__((ext_vector_type(8)));
typedef _Float16 f16x4 __attribute__((ext_vector_type(4)));
typedef _Float16 f16x2 __attribute__((ext_vector_type(2)));
typedef float f32x4 __attribute__((ext_vector_type(4)));

// async global->LDS, 16B per lane, wave-uniform LDS base + lane*16
#define GLOAD_LDS16(gp, lp)                                        \
    __builtin_amdgcn_global_load_lds(                              \
        (const __attribute__((address_space(1))) void*)(gp),       \
        (__attribute__((address_space(3))) void*)(lp), 16, 0, 0)

// ---------------- utility zero kernels ----------------
__global__ void zero_int_kernel(int* p, int n) {
    int i = blockIdx.x * blockDim.x + threadIdx.x;
    if (i < n) p[i] = 0;
}
__global__ void zero_float_kernel(float* p, int n) {
    int i = blockIdx.x * blockDim.x + threadIdx.x;
    if (i < n) p[i] = 0.0f;
}

// ---------------- CSR build ----------------
__global__ void deg_kernel(const int* __restrict__ dst, int* __restrict__ deg, int e) {
    int i = blockIdx.x * blockDim.x + threadIdx.x;
    if (i < e) atomicAdd(&deg[dst[i]], 1);
}

// single-tile scan: each thread owns 32 contiguous elements (int4 loads),
// then one 1024-wide Hillis-Steele pass
__global__ __launch_bounds__(1024) void scan_kernel(
    const int* __restrict__ deg, int* __restrict__ row_start,
    int* __restrict__ pos, int n)
{
    __shared__ int smem[1024];
    const int t = threadIdx.x;
    const int base = t * 32;  // 1024*32 = 32768 >= 30000
    int loc[32];
    int s = 0;
#pragma unroll
    for (int g = 0; g < 8; ++g) {
        int idx = base + g * 4;
        int4 d4;
        if (idx + 3 < n) {
            d4 = *(const int4*)(deg + idx);
        } else {
            d4.x = (idx + 0 < n) ? deg[idx + 0] : 0;
            d4.y = (idx + 1 < n) ? deg[idx + 1] : 0;
            d4.z = (idx + 2 < n) ? deg[idx + 2] : 0;
            d4.w = (idx + 3 < n) ? deg[idx + 3] : 0;
        }
        loc[g * 4 + 0] = s; s += d4.x;
        loc[g * 4 + 1] = s; s += d4.y;
        loc[g * 4 + 2] = s; s += d4.z;
        loc[g * 4 + 3] = s; s += d4.w;
    }
    smem[t] = s;
    __syncthreads();
    for (int off = 1; off < 1024; off <<= 1) {
        int tv = 0;
        if (t >= off) tv = smem[t - off];
        __syncthreads();
        smem[t] += tv;
        __syncthreads();
    }
    const int excl = smem[t] - s;
#pragma unroll
    for (int g = 0; g < 32; ++g) {
        int idx = base + g;
        if (idx < n) {
            int r = excl + loc[g];
            row_start[idx] = r;
            pos[idx] = r;
        }
    }
    if (t == 1023) row_start[n] = smem[1023];
}

__global__ void fill_kernel(const int* __restrict__ src, const int* __restrict__ dst,
                            int* __restrict__ pos, int* __restrict__ csr_src, int e) {
    int i = blockIdx.x * blockDim.x + threadIdx.x;
    if (i < e) {
        int p = atomicAdd(&pos[dst[i]], 1);
        csr_src[p] = src[i];
    }
}

// ---------------- conversion kernels ----------------
__global__ void cvt_f32_f16_kernel(const float* __restrict__ in, _Float16* __restrict__ out, long n8) {
    long i = blockIdx.x * (long)blockDim.x + threadIdx.x;
    if (i >= n8) return;
    float4 a = ((const float4*)in)[2 * i];
    float4 b = ((const float4*)in)[2 * i + 1];
    f16x8 o = {(_Float16)a.x, (_Float16)a.y, (_Float16)a.z, (_Float16)a.w,
               (_Float16)b.x, (_Float16)b.y, (_Float16)b.z, (_Float16)b.w};
    ((f16x8*)out)[i] = o;
}

__global__ void tcvt_kernel(const float* __restrict__ in, _Float16* __restrict__ outT, int K, int N) {
    int n = blockIdx.x * blockDim.x + threadIdx.x;
    int k = blockIdx.y;
    if (n < N) outT[(long)n * K + k] = (_Float16)in[(long)k * N + n];
}

// ---------------- weight folds: kp = (x@Wk+bk)@BD(k_rel) == x@(Wk@BD) + bk@BD ----
// layer1: W [512][768], k_rel/v_rel [4][64][64] blockdiag. out BT [768][512] f16.
__global__ void foldw1_kernel(const float* __restrict__ W,
                              const float* __restrict__ krel,
                              const float* __restrict__ vrel,
                              _Float16* __restrict__ BT) {
    int k = blockIdx.x * blockDim.x + threadIdx.x;  // 0..511 (input row)
    int n = blockIdx.y;                             // 0..767 (output col)
    if (k >= 512) return;
    float acc;
    if (n < 256) {
        int h = n >> 6, e = n & 63;
        const float* wr = W + (long)k * 768 + h * 64;
        const float* kr = krel + h * 4096 + e;
        acc = 0.f;
        for (int d = 0; d < 64; ++d) acc += wr[d] * kr[(long)d * 64];
    } else if (n < 512) {
        acc = W[(long)k * 768 + n];
    } else {
        int m = n - 512, h = m >> 6, e = m & 63;
        const float* wr = W + (long)k * 768 + 512 + h * 64;
        const float* vr = vrel + h * 4096 + e;
        acc = 0.f;
        for (int d = 0; d < 64; ++d) acc += wr[d] * vr[(long)d * 64];
    }
    BT[(long)n * 512 + k] = (_Float16)acc;
}

__global__ void foldb1_kernel(const float* __restrict__ b, const float* __restrict__ krel,
                              const float* __restrict__ vrel, float* __restrict__ bf) {
    int n = blockIdx.x * blockDim.x + threadIdx.x;
    if (n >= 768) return;
    float acc;
    if (n < 256) {
        int h = n >> 6, e = n & 63;
        acc = 0.f;
        for (int d = 0; d < 64; ++d) acc += b[h * 64 + d] * krel[h * 4096 + d * 64 + e];
    } else if (n < 512) {
        acc = b[n];
    } else {
        int m = n - 512, h = m >> 6, e = m & 63;
        acc = 0.f;
        for (int d = 0; d < 64; ++d) acc += b[512 + h * 64 + d] * vrel[h * 4096 + d * 64 + e];
    }
    bf[n] = acc;
}

// layer2: W [256][768], k_rel2/v_rel2 [256][256] dense. out BT [768][256] f16.
__global__ void foldw2_kernel(const float* __restrict__ W,
                              const float* __restrict__ krel2,
                              const float* __restrict__ vrel2,
                              _Float16* __restrict__ BT) {
    int k = blockIdx.x * blockDim.x + threadIdx.x;  // 0..255
    int n = blockIdx.y;                             // 0..767
    if (k >= 256) return;
    float acc;
    if (n < 256) {
        const float* wr = W + (long)k * 768;
        const float* kr = krel2 + n;
        acc = 0.f;
        for (int d = 0; d < 256; ++d) acc += wr[d] * kr[(long)d * 256];
    } else if (n < 512) {
        acc = W[(long)k * 768 + n];
    } else {
        const float* wr = W + (long)k * 768 + 512;
        const float* vr = vrel2 + (n - 512);
        acc = 0.f;
        for (int d = 0; d < 256; ++d) acc += wr[d] * vr[(long)d * 256];
    }
    BT[(long)n * 256 + k] = (_Float16)acc;
}

__global__ void foldb2_kernel(const float* __restrict__ b, const float* __restrict__ krel2,
                              const float* __restrict__ vrel2, float* __restrict__ bf) {
    int n = blockIdx.x * blockDim.x + threadIdx.x;
    if (n >= 768) return;
    float acc;
    if (n < 256) {
        acc = 0.f;
        for (int d = 0; d < 256; ++d) acc += b[d] * krel2[(long)d * 256 + n];
    } else if (n < 512) {
        acc = b[n];
    } else {
        acc = 0.f;
        for (int d = 0; d < 256; ++d) acc += b[512 + d] * vrel2[(long)d * 256 + (n - 512)];
    }
    bf[n] = acc;
}

// ---------------- fp16 MFMA GEMM: global_load_lds staging, linear [128][32] LDS.
// Epilogues: f16 out (Ch) | f16 residual blend | fused BN col-stats |
// HGT split (cols 0-255 -> kv[row][c], 256-511 -> qout[row][c-256],
//            512-767 -> kv[row][256 + c-512]) ----------------
__global__ __launch_bounds__(256) void mfma_gemm_kernel(
    const _Float16* __restrict__ A, int lda,
    const _Float16* __restrict__ BT,
    float* __restrict__ Cf,
    _Float16* __restrict__ Ch,
    int ldc, int M, int N, int K,
    const float* __restrict__ bias,
    const _Float16* __restrict__ res,   // f16 residual (skip blend), ld = ldc
    const float* __restrict__ skip,
    float* __restrict__ bn_accum,       // [512]: col sums then col sqsums
    _Float16* __restrict__ kv_out,      // HGT split: [M][512] f16 (K|V)
    _Float16* __restrict__ q_out)       // HGT split: [M][256] f16
{
    __shared__ __align__(16) _Float16 As[128][32];
    __shared__ __align__(16) _Float16 Bs[128][32];
    const int tid = threadIdx.x;
    const int bm = blockIdx.y * 128, bn = blockIdx.x * 128;
    const int wave = tid >> 6, lane = tid & 63;
    const int wr = wave >> 1, wc = wave & 1;
    const int l16 = lane & 15, quad = lane >> 4;

    // staging chunk map: chunk c (0..511) of 16B -> LDS byte c*16 -> row=c>>2, col8=(c&3)*8
    const int r0 = tid >> 2, kc0 = (tid & 3) * 8;
    const int r1 = r0 + 64;
    int gra0 = bm + r0; if (gra0 >= M) gra0 = M - 1;  // DMA has no predication;
    int gra1 = bm + r1; if (gra1 >= M) gra1 = M - 1;  // C-store is row-guarded
    const _Float16* a0 = A + (long)gra0 * lda + kc0;
    const _Float16* a1 = A + (long)gra1 * lda + kc0;
    const _Float16* b0 = BT + (long)(bn + r0) * K + kc0;
    const _Float16* b1 = BT + (long)(bn + r1) * K + kc0;

    auto ldsA = (__attribute__((address_space(3))) char*)&As[0][0];
    auto ldsB = (__attribute__((address_space(3))) char*)&Bs[0][0];
    const int wb = wave * 1024;  // wave-uniform LDS base (lane*16 added by HW)

    f32x4 acc[4][4] = {};

    for (int k0 = 0; k0 < K; k0 += 32) {
        GLOAD_LDS16(a0 + k0, ldsA + wb);
        GLOAD_LDS16(a1 + k0, ldsA + 4096 + wb);
        GLOAD_LDS16(b0 + k0, ldsB + wb);
        GLOAD_LDS16(b1 + k0, ldsB + 4096 + wb);
        __syncthreads();
        f16x8 af[4], bf[4];
#pragma unroll
        for (int i = 0; i < 4; ++i)
            af[i] = *(const f16x8*)&As[64 * wr + 16 * i + l16][quad * 8];
#pragma unroll
        for (int j = 0; j < 4; ++j)
            bf[j] = *(const f16x8*)&Bs[64 * wc + 16 * j + l16][quad * 8];
#pragma unroll
        for (int i = 0; i < 4; ++i)
#pragma unroll
            for (int j = 0; j < 4; ++j)
                acc[i][j] = __builtin_amdgcn_mfma_f32_16x16x32_f16(af[i], bf[j], acc[i][j], 0, 0, 0);
        __syncthreads();
    }

    float s = 1.0f, om = 0.0f;
    if (skip) {
        float sv = 1.0f / (1.0f + __expf(-skip[0]));
        s = sv; om = 1.0f - sv;
    }
    float cs[4] = {}, cq[4] = {};
#pragma unroll
    for (int i = 0; i < 4; ++i) {
        int gr0 = bm + 64 * wr + 16 * i + quad * 4;
#pragma unroll
        for (int j = 0; j < 4; ++j) {
            int gc = bn + 64 * wc + 16 * j + l16;
            float bv = bias ? bias[gc] : 0.0f;
#pragma unroll
            for (int r = 0; r < 4; ++r) {
                int row = gr0 + r;
                if (row >= M) continue;
                float v = acc[i][j][r] + bv;
                if (res) v = s * v + om * (float)res[(long)row * ldc + gc];
                if (Cf) Cf[(long)row * ldc + gc] = v;
                if (Ch) Ch[(long)row * ldc + gc] = (_Float16)v;
                if (kv_out) {
                    _Float16 hv = (_Float16)v;
                    if (gc < 256)       kv_out[(long)row * 512 + gc] = hv;         // K
                    else if (gc < 512)  q_out[(long)row * 256 + (gc - 256)] = hv;  // Q
                    else                kv_out[(long)row * 512 + (gc - 256)] = hv; // V at 256+
                }
                if (bn_accum) { cs[j] += v; cq[j] += v * v; }
            }
        }
    }
    if (bn_accum) {
        // LDS reduce: 8 slots (wr*4+quad) per local column, overlay on As/Bs
        float* redS = (float*)&As[0][0];  // 128*8 floats = 4KB (<=8KB)
        float* redQ = (float*)&Bs[0][0];
        int slot = wr * 4 + quad;
#pragma unroll
        for (int j = 0; j < 4; ++j) {
            int cl = 64 * wc + 16 * j + l16;
            redS[cl * 8 + slot] = cs[j];
            redQ[cl * 8 + slot] = cq[j];
        }
        __syncthreads();
        if (tid < 128) {
            float ssum = 0.f, qsum = 0.f;
#pragma unroll
            for (int t = 0; t < 8; ++t) {
                ssum += redS[tid * 8 + t];
                qsum += redQ[tid * 8 + t];
            }
            atomicAdd(&bn_accum[bn + tid], ssum);
            atomicAdd(&bn_accum[256 + bn + tid], qsum);
        }
    }
}

// ---------------- attention: compact kv table ([K|V] 1024B rows, no q pollution);
// one wave per node, 32-lane halves split edges, shfl_xor(32) state merge;
// fdot2, deferred-max rescale, fused GELU ----------------
template <int H>
__global__ __launch_bounds__(256) void attn_f16kv_kernel(
    const _Float16* __restrict__ qbase,                 // [n][256] f16
    const _Float16* __restrict__ kv,                    // [n][512] f16 = [K|V]
    const float* __restrict__ p_rel,
    const int* __restrict__ row_start, const int* __restrict__ csr_src,
    _Float16* __restrict__ agg, int n)
{
    constexpr int D = 256 / H;
    constexpr int GL = D / 8;  // lanes per head group (8 ch per lane)
    int node = blockIdx.x * 4 + (threadIdx.x >> 6);  // one wave per node
    int lane = threadIdx.x & 63;
    int half = lane >> 5;     // edge-list half
    int l32 = lane & 31;      // channel lane within half
    if (node >= n) return;
    const int head = l32 / GL;
    const float scale = p_rel[head] * rsqrtf((float)D);
    const int ch = l32 * 8;  // == head*D + (l32%GL)*8 for both H=1,4
    f16x8 qv = *(const f16x8*)(qbase + (long)node * 256 + ch);
    f16x2 qp[4];
#pragma unroll
    for (int j = 0; j < 4; ++j) { qp[j][0] = qv[2 * j]; qp[j][1] = qv[2 * j + 1]; }

    const _Float16* kpc = kv + ch;         // K channels at row+[0,256)
    const _Float16* vpc = kv + 256 + ch;   // V channels at row+[256,512)
    int e0all = row_start[node], e1all = row_start[node + 1];
    int c0 = (e1all - e0all + 1) >> 1;      // first-half count (ceil)
    int e0 = half ? (e0all + c0) : e0all;
    int e1 = half ? e1all : (e0all + c0);

    float m = -1e30f, lsum = 0.0f;
    float a[8] = {};

    int e = e0;
    for (; e + 1 < e1; e += 2) {
        int s0 = csr_src[e], s1 = csr_src[e + 1];
        f16x8 k0 = *(const f16x8*)(kpc + (long)s0 * 512);
        f16x8 k1 = *(const f16x8*)(kpc + (long)s1 * 512);
        f16x8 v0 = *(const f16x8*)(vpc + (long)s0 * 512);
        f16x8 v1 = *(const f16x8*)(vpc + (long)s1 * 512);
        float d0 = 0.0f, d1 = 0.0f;
#pragma unroll
        for (int j = 0; j < 4; ++j) {
            f16x2 k0p = {k0[2 * j], k0[2 * j + 1]};
            f16x2 k1p = {k1[2 * j], k1[2 * j + 1]};
            d0 = __builtin_amdgcn_fdot2(qp[j], k0p, d0, false);
            d1 = __builtin_amdgcn_fdot2(qp[j], k1p, d1, false);
        }
#pragma unroll
        for (int off = 1; off < GL; off <<= 1) {
            d0 += __shfl_xor(d0, off);
            d1 += __shfl_xor(d1, off);
        }
        float al0 = d0 * scale, al1 = d1 * scale;
        float mx = fmaxf(al0, al1);
        float diff = mx - m;
        if (__builtin_expect(diff > 8.0f, 0)) {  // deferred-max rescale (rare)
            float corr = __expf(-diff);
            lsum *= corr;
#pragma unroll
            for (int j = 0; j < 8; ++j) a[j] *= corr;
            m = mx;
        }
        float w0 = __expf(al0 - m), w1 = __expf(al1 - m);
        lsum += w0 + w1;
#pragma unroll
        for (int j = 0; j < 8; ++j)
            a[j] += w0 * (float)v0[j] + w1 * (float)v1[j];
    }
    if (e < e1) {
        int s0 = csr_src[e];
        f16x8 k0 = *(const f16x8*)(kpc + (long)s0 * 512);
        f16x8 v0 = *(const f16x8*)(vpc + (long)s0 * 512);
        float d0 = 0.0f;
#pragma unroll
        for (int j = 0; j < 4; ++j) {
            f16x2 k0p = {k0[2 * j], k0[2 * j + 1]};
            d0 = __builtin_amdgcn_fdot2(qp[j], k0p, d0, false);
        }
#pragma unroll
        for (int off = 1; off < GL; off <<= 1) d0 += __shfl_xor(d0, off);
        float al0 = d0 * scale;
        float diff = al0 - m;
        if (__builtin_expect(diff > 8.0f, 0)) {
            float corr = __expf(-diff);
            lsum *= corr;
#pragma unroll
            for (int j = 0; j < 8; ++j) a[j] *= corr;
            m = al0;
        }
        float w0 = __expf(al0 - m);
        lsum += w0;
#pragma unroll
        for (int j = 0; j < 8; ++j) a[j] += w0 * (float)v0[j];
    }

    // merge the two halves' online-softmax states (cross-32 shuffles)
    float m_o = __shfl_xor(m, 32);
    float ls_o = __shfl_xor(lsum, 32);
    float mm = fmaxf(m, m_o);
    float wsf = __expf(m - mm), wo = __expf(m_o - mm);
    lsum = lsum * wsf + ls_o * wo;
#pragma unroll
    for (int j = 0; j < 8; ++j) {
        float a_o = __shfl_xor(a[j], 32);
        a[j] = a[j] * wsf + a_o * wo;
    }

    if (half == 0) {
        float inv = 1.0f / (lsum + 1e-16f);
        f16x8 o;
#pragma unroll
        for (int j = 0; j < 8; ++j) {
            float v = a[j] * inv;
            v = 0.5f * v * (1.0f + erff(v * 0.70710678118654752f));
            o[j] = (_Float16)v;
        }
        *(f16x8*)(agg + (long)node * 256 + ch) = o;
    }
}

// ---------------- BatchNorm apply (f16 in -> f16 out, stats fused in out1) ----
__global__ void bn_apply_kernel(const _Float16* __restrict__ hin, _Float16* __restrict__ hbn,
                                const float* __restrict__ stats,
                                const float* __restrict__ gamma, const float* __restrict__ beta) {
    long idx = blockIdx.x * (long)blockDim.x + threadIdx.x;  // NN*32 f16x8 groups
    if (idx >= (long)NN * 32) return;
    int cg = (int)(idx & 31) * 8;
    f16x8 hv = ((const f16x8*)hin)[idx];
    const float invn = 1.0f / 30000.0f;
    f16x8 o;
#pragma unroll
    for (int r = 0; r < 8; ++r) {
        int c = cg + r;
        float mu = stats[c] * invn;
        float var = stats[256 + c] * invn - mu * mu;
        float v = ((float)hv[r] - mu) * rsqrtf(var + 1e-5f) * gamma[c] + beta[c];
        o[r] = (_Float16)fmaxf(v, 0.0f);
    }
    ((f16x8*)hbn)[idx] = o;
}

// ---------------- launch ----------------
extern "C" void kernel_launch(void* const* d_in, const int* in_sizes, int n_in,
                              void* d_out, int out_size, void* d_ws, size_t ws_size,
                              hipStream_t stream) {
    const float* x       = (const float*)d_in[0];
    const int*   ei      = (const int*)d_in[1];
    const float* w_kqv1  = (const float*)d_in[2];
    const float* b_kqv1  = (const float*)d_in[3];
    const float* k_rel1  = (const float*)d_in[4];
    const float* v_rel1  = (const float*)d_in[5];
    const float* p_rel1  = (const float*)d_in[6];
    const float* w_out1  = (const float*)d_in[7];
    const float* b_out1  = (const float*)d_in[8];
    const float* bn_gamma = (const float*)d_in[10];
    const float* bn_beta  = (const float*)d_in[11];
    const float* w_kqv2  = (const float*)d_in[12];
    const float* b_kqv2  = (const float*)d_in[13];
    const float* k_rel2  = (const float*)d_in[14];
    const float* v_rel2  = (const float*)d_in[15];
    const float* p_rel2  = (const float*)d_in[16];
    const float* w_out2  = (const float*)d_in[17];
    const float* b_out2  = (const float*)d_in[18];
    const float* skip2   = (const float*)d_in[19];
    float* out = (float*)d_out;

    char* p = (char*)d_ws;
    auto alloc = [&](size_t bytes) -> void* {
        void* r = (void*)p;
        p += (bytes + 255) & ~(size_t)255;
        return r;
    };
    _Float16* x_h   = (_Float16*)alloc((size_t)NN * 512 * 2);   // 30.72 MB
    _Float16* kv_h  = (_Float16*)alloc((size_t)NN * 512 * 2);   // 30.72 (compact [K|V])
    _Float16* q_h   = (_Float16*)alloc((size_t)NN * 256 * 2);   // 15.36
    _Float16* agg_h = (_Float16*)alloc((size_t)NN * 256 * 2);   // 15.36
    _Float16* h16   = (_Float16*)alloc((size_t)NN * 256 * 2);   // 15.36 (pre-BN out1)
    _Float16* hbn_h = (_Float16*)alloc((size_t)NN * 256 * 2);   // 15.36 (post-BN/ReLU)
    _Float16* w1T    = (_Float16*)alloc((size_t)768 * 512 * 2);
    _Float16* wout1T = (_Float16*)alloc((size_t)256 * 256 * 2);
    _Float16* w2T    = (_Float16*)alloc((size_t)768 * 256 * 2);
    _Float16* wout2T = (_Float16*)alloc((size_t)256 * 256 * 2);
    float* bf1       = (float*)alloc(768 * 4);
    float* bf2       = (float*)alloc(768 * 4);
    int*   deg       = (int*)alloc((size_t)NN * 4);
    int*   row_start = (int*)alloc((size_t)(NN + 1) * 4);
    int*   pos       = (int*)alloc((size_t)NN * 4);
    int*   csr_src   = (int*)alloc((size_t)NE * 4);
    float* bnstats   = (float*)alloc(512 * 4);   // [256 sums | 256 sqsums]

    const int* esrc = ei;
    const int* edst = ei + NE;

    // ---- conversions + weight folds ----
    cvt_f32_f16_kernel<<<(NN * 512 / 8 + 255) / 256, 256, 0, stream>>>(x, x_h, (long)NN * 512 / 8);
    foldw1_kernel<<<dim3(2, 768), 256, 0, stream>>>(w_kqv1, k_rel1, v_rel1, w1T);
    foldb1_kernel<<<3, 256, 0, stream>>>(b_kqv1, k_rel1, v_rel1, bf1);
    tcvt_kernel<<<dim3(1, 256), 256, 0, stream>>>(w_out1, wout1T, 256, 256);
    foldw2_kernel<<<dim3(1, 768), 256, 0, stream>>>(w_kqv2, k_rel2, v_rel2, w2T);
    foldb2_kernel<<<3, 256, 0, stream>>>(b_kqv2, k_rel2, v_rel2, bf2);
    tcvt_kernel<<<dim3(1, 256), 256, 0, stream>>>(w_out2, wout2T, 256, 256);

    // ---- CSR build ----
    zero_int_kernel<<<(NN + 255) / 256, 256, 0, stream>>>(deg, NN);
    deg_kernel<<<(NE + 255) / 256, 256, 0, stream>>>(edst, deg, NE);
    scan_kernel<<<1, 1024, 0, stream>>>(deg, row_start, pos, NN);
    fill_kernel<<<(NE + 255) / 256, 256, 0, stream>>>(esrc, edst, pos, csr_src, NE);

    const int MB = (NN + 127) / 128;

    // ---- layer 1: kqv GEMM scatters directly to compact kv/q tables ----
    mfma_gemm_kernel<<<dim3(6, MB), 256, 0, stream>>>(
        x_h, 512, w1T, nullptr, nullptr, 768, NN, 768, 512, bf1, nullptr, nullptr,
        nullptr, kv_h, q_h);
    attn_f16kv_kernel<4><<<(NN + 3) / 4, 256, 0, stream>>>(
        q_h, kv_h, p_rel1, row_start, csr_src, agg_h, NN);

    // out1: f16 out + fused BN column stats
    zero_float_kernel<<<2, 256, 0, stream>>>(bnstats, 512);
    mfma_gemm_kernel<<<dim3(2, MB), 256, 0, stream>>>(
        agg_h, 256, wout1T, nullptr, h16, 256, NN, 256, 256, b_out1, nullptr, nullptr,
        bnstats, nullptr, nullptr);

    // ---- BatchNorm apply + ReLU (f16 -> f16) ----
    bn_apply_kernel<<<(NN * 32 + 255) / 256, 256, 0, stream>>>(h16, hbn_h, bnstats, bn_gamma, bn_beta);

    // ---- layer 2 ----
    mfma_gemm_kernel<<<dim3(6, MB), 256, 0, stream>>>(
        hbn_h, 256, w2T, nullptr, nullptr, 768, NN, 768, 256, bf2, nullptr, nullptr,
        nullptr, kv_h, q_h);
    attn_f16kv_kernel<1><<<(NN + 3) / 4, 256, 0, stream>>>(
        q_h, kv_h, p_rel2, row_start, csr_src, agg_h, NN);
    // out2 + skip (residual = post-BN/ReLU hbn, f16)
    mfma_gemm_kernel<<<dim3(2, MB), 256, 0, stream>>>(
        agg_h, 256, wout2T, out, nullptr, 256, NN, 256, 256, b_out2, hbn_h, skip2,
        nullptr, nullptr, nullptr);
}

// Round 8
// 603.851 us; speedup vs baseline: 1.0215x; 1.0215x over previous
//
#include <hip/hip_runtime.h>
#include <math.h>

#define NN 30000
#define NE 480000

typedef _Float16 f16x8 __attribute__((ext_vector_type(8)));
typedef _Float16 f16x4 __attribute__((ext_vector_type(4)));
typedef _Float16 f16x2 __attribute__((ext_vector_type(2)));
typedef float f32x4 __attribute__((ext_vector_type(4)));

// async global->LDS, 16B per lane, wave-uniform LDS base + lane*16
#define GLOAD_LDS16(gp, lp)                                        \
    __builtin_amdgcn_global_load_lds(                              \
        (const __attribute__((address_space(1))) void*)(gp),       \
        (__attribute__((address_space(3))) void*)(lp), 16, 0, 0)

// ---------------- utility zero kernels ----------------
__global__ void zero_int_kernel(int* p, int n) {
    int i = blockIdx.x * blockDim.x + threadIdx.x;
    if (i < n) p[i] = 0;
}
__global__ void zero_float_kernel(float* p, int n) {
    int i = blockIdx.x * blockDim.x + threadIdx.x;
    if (i < n) p[i] = 0.0f;
}

// ---------------- CSR build ----------------
__global__ void deg_kernel(const int* __restrict__ dst, int* __restrict__ deg, int e) {
    int i = blockIdx.x * blockDim.x + threadIdx.x;
    if (i < e) atomicAdd(&deg[dst[i]], 1);
}

// single-tile scan: each thread owns 32 contiguous elements (int4 loads),
// then one 1024-wide Hillis-Steele pass
__global__ __launch_bounds__(1024) void scan_kernel(
    const int* __restrict__ deg, int* __restrict__ row_start,
    int* __restrict__ pos, int n)
{
    __shared__ int smem[1024];
    const int t = threadIdx.x;
    const int base = t * 32;  // 1024*32 = 32768 >= 30000
    int loc[32];
    int s = 0;
#pragma unroll
    for (int g = 0; g < 8; ++g) {
        int idx = base + g * 4;
        int4 d4;
        if (idx + 3 < n) {
            d4 = *(const int4*)(deg + idx);
        } else {
            d4.x = (idx + 0 < n) ? deg[idx + 0] : 0;
            d4.y = (idx + 1 < n) ? deg[idx + 1] : 0;
            d4.z = (idx + 2 < n) ? deg[idx + 2] : 0;
            d4.w = (idx + 3 < n) ? deg[idx + 3] : 0;
        }
        loc[g * 4 + 0] = s; s += d4.x;
        loc[g * 4 + 1] = s; s += d4.y;
        loc[g * 4 + 2] = s; s += d4.z;
        loc[g * 4 + 3] = s; s += d4.w;
    }
    smem[t] = s;
    __syncthreads();
    for (int off = 1; off < 1024; off <<= 1) {
        int tv = 0;
        if (t >= off) tv = smem[t - off];
        __syncthreads();
        smem[t] += tv;
        __syncthreads();
    }
    const int excl = smem[t] - s;
#pragma unroll
    for (int g = 0; g < 32; ++g) {
        int idx = base + g;
        if (idx < n) {
            int r = excl + loc[g];
            row_start[idx] = r;
            pos[idx] = r;
        }
    }
    if (t == 1023) row_start[n] = smem[1023];
}

__global__ void fill_kernel(const int* __restrict__ src, const int* __restrict__ dst,
                            int* __restrict__ pos, int* __restrict__ csr_src, int e) {
    int i = blockIdx.x * blockDim.x + threadIdx.x;
    if (i < e) {
        int p = atomicAdd(&pos[dst[i]], 1);
        csr_src[p] = src[i];
    }
}

// ---------------- conversion kernels ----------------
__global__ void cvt_f32_f16_kernel(const float* __restrict__ in, _Float16* __restrict__ out, long n8) {
    long i = blockIdx.x * (long)blockDim.x + threadIdx.x;
    if (i >= n8) return;
    float4 a = ((const float4*)in)[2 * i];
    float4 b = ((const float4*)in)[2 * i + 1];
    f16x8 o = {(_Float16)a.x, (_Float16)a.y, (_Float16)a.z, (_Float16)a.w,
               (_Float16)b.x, (_Float16)b.y, (_Float16)b.z, (_Float16)b.w};
    ((f16x8*)out)[i] = o;
}

__global__ void tcvt_kernel(const float* __restrict__ in, _Float16* __restrict__ outT, int K, int N) {
    int n = blockIdx.x * blockDim.x + threadIdx.x;
    int k = blockIdx.y;
    if (n < N) outT[(long)n * K + k] = (_Float16)in[(long)k * N + n];
}

// ---------------- weight folds, output column order [K | V | Q] ----------------
// layer1: W [512][768] (cols: K 0-255, Q 256-511, V 512-767),
// k_rel/v_rel [4][64][64] blockdiag. out BT [768][512] f16, rows = [K|V|Q].
__global__ void foldw1_kernel(const float* __restrict__ W,
                              const float* __restrict__ krel,
                              const float* __restrict__ vrel,
                              _Float16* __restrict__ BT) {
    int k = blockIdx.x * blockDim.x + threadIdx.x;  // 0..511 (input row)
    int n = blockIdx.y;                             // 0..767 (output col, K|V|Q order)
    if (k >= 512) return;
    float acc;
    if (n < 256) {  // K' = Wk @ BD(krel)
        int h = n >> 6, e = n & 63;
        const float* wr = W + (long)k * 768 + h * 64;
        const float* kr = krel + h * 4096 + e;
        acc = 0.f;
        for (int d = 0; d < 64; ++d) acc += wr[d] * kr[(long)d * 64];
    } else if (n < 512) {  // V' = Wv @ BD(vrel)
        int m = n - 256, h = m >> 6, e = m & 63;
        const float* wr = W + (long)k * 768 + 512 + h * 64;
        const float* vr = vrel + h * 4096 + e;
        acc = 0.f;
        for (int d = 0; d < 64; ++d) acc += wr[d] * vr[(long)d * 64];
    } else {  // Q (identity), W cols 256..511
        acc = W[(long)k * 768 + (n - 256)];
    }
    BT[(long)n * 512 + k] = (_Float16)acc;
}

__global__ void foldb1_kernel(const float* __restrict__ b, const float* __restrict__ krel,
                              const float* __restrict__ vrel, float* __restrict__ bf) {
    int n = blockIdx.x * blockDim.x + threadIdx.x;
    if (n >= 768) return;
    float acc;
    if (n < 256) {
        int h = n >> 6, e = n & 63;
        acc = 0.f;
        for (int d = 0; d < 64; ++d) acc += b[h * 64 + d] * krel[h * 4096 + d * 64 + e];
    } else if (n < 512) {
        int m = n - 256, h = m >> 6, e = m & 63;
        acc = 0.f;
        for (int d = 0; d < 64; ++d) acc += b[512 + h * 64 + d] * vrel[h * 4096 + d * 64 + e];
    } else {
        acc = b[n - 256];
    }
    bf[n] = acc;
}

// layer2: W [256][768], k_rel2/v_rel2 [256][256] dense. out BT [768][256], rows [K|V|Q].
__global__ void foldw2_kernel(const float* __restrict__ W,
                              const float* __restrict__ krel2,
                              const float* __restrict__ vrel2,
                              _Float16* __restrict__ BT) {
    int k = blockIdx.x * blockDim.x + threadIdx.x;  // 0..255
    int n = blockIdx.y;                             // 0..767 (K|V|Q order)
    if (k >= 256) return;
    float acc;
    if (n < 256) {  // K'
        const float* wr = W + (long)k * 768;
        const float* kr = krel2 + n;
        acc = 0.f;
        for (int d = 0; d < 256; ++d) acc += wr[d] * kr[(long)d * 256];
    } else if (n < 512) {  // V'
        const float* wr = W + (long)k * 768 + 512;
        const float* vr = vrel2 + (n - 256);
        acc = 0.f;
        for (int d = 0; d < 256; ++d) acc += wr[d] * vr[(long)d * 256];
    } else {  // Q
        acc = W[(long)k * 768 + (n - 256)];
    }
    BT[(long)n * 256 + k] = (_Float16)acc;
}

__global__ void foldb2_kernel(const float* __restrict__ b, const float* __restrict__ krel2,
                              const float* __restrict__ vrel2, float* __restrict__ bf) {
    int n = blockIdx.x * blockDim.x + threadIdx.x;
    if (n >= 768) return;
    float acc;
    if (n < 256) {
        acc = 0.f;
        for (int d = 0; d < 256; ++d) acc += b[d] * krel2[(long)d * 256 + n];
    } else if (n < 512) {
        acc = 0.f;
        for (int d = 0; d < 256; ++d) acc += b[512 + d] * vrel2[(long)d * 256 + (n - 256)];
    } else {
        acc = b[n - 256];
    }
    bf[n] = acc;
}

// ---------------- fp16 MFMA GEMM: global_load_lds staging, linear [128][32] LDS,
// optional f16 residual blend + optional fused BN column-stats epilogue
// (verified round-6 configuration) ----------------
__global__ __launch_bounds__(256) void mfma_gemm_kernel(
    const _Float16* __restrict__ A, int lda,
    const _Float16* __restrict__ BT,
    float* __restrict__ Cf,
    _Float16* __restrict__ Ch,
    int ldc, int M, int N, int K,
    const float* __restrict__ bias,
    const _Float16* __restrict__ res,   // f16 residual (skip blend), ld = ldc
    const float* __restrict__ skip,
    float* __restrict__ bn_accum)       // [512]: col sums then col sqsums
{
    __shared__ __align__(16) _Float16 As[128][32];
    __shared__ __align__(16) _Float16 Bs[128][32];
    const int tid = threadIdx.x;
    const int bm = blockIdx.y * 128, bn = blockIdx.x * 128;
    const int wave = tid >> 6, lane = tid & 63;
    const int wr = wave >> 1, wc = wave & 1;
    const int l16 = lane & 15, quad = lane >> 4;

    // staging chunk map: chunk c (0..511) of 16B -> LDS byte c*16 -> row=c>>2, col8=(c&3)*8
    const int r0 = tid >> 2, kc0 = (tid & 3) * 8;
    const int r1 = r0 + 64;
    int gra0 = bm + r0; if (gra0 >= M) gra0 = M - 1;  // DMA has no predication;
    int gra1 = bm + r1; if (gra1 >= M) gra1 = M - 1;  // C-store is row-guarded
    const _Float16* a0 = A + (long)gra0 * lda + kc0;
    const _Float16* a1 = A + (long)gra1 * lda + kc0;
    const _Float16* b0 = BT + (long)(bn + r0) * K + kc0;
    const _Float16* b1 = BT + (long)(bn + r1) * K + kc0;

    auto ldsA = (__attribute__((address_space(3))) char*)&As[0][0];
    auto ldsB = (__attribute__((address_space(3))) char*)&Bs[0][0];
    const int wb = wave * 1024;  // wave-uniform LDS base (lane*16 added by HW)

    f32x4 acc[4][4] = {};

    for (int k0 = 0; k0 < K; k0 += 32) {
        GLOAD_LDS16(a0 + k0, ldsA + wb);
        GLOAD_LDS16(a1 + k0, ldsA + 4096 + wb);
        GLOAD_LDS16(b0 + k0, ldsB + wb);
        GLOAD_LDS16(b1 + k0, ldsB + 4096 + wb);
        __syncthreads();
        f16x8 af[4], bf[4];
#pragma unroll
        for (int i = 0; i < 4; ++i)
            af[i] = *(const f16x8*)&As[64 * wr + 16 * i + l16][quad * 8];
#pragma unroll
        for (int j = 0; j < 4; ++j)
            bf[j] = *(const f16x8*)&Bs[64 * wc + 16 * j + l16][quad * 8];
#pragma unroll
        for (int i = 0; i < 4; ++i)
#pragma unroll
            for (int j = 0; j < 4; ++j)
                acc[i][j] = __builtin_amdgcn_mfma_f32_16x16x32_f16(af[i], bf[j], acc[i][j], 0, 0, 0);
        __syncthreads();
    }

    float s = 1.0f, om = 0.0f;
    if (skip) {
        float sv = 1.0f / (1.0f + __expf(-skip[0]));
        s = sv; om = 1.0f - sv;
    }
    float cs[4] = {}, cq[4] = {};
#pragma unroll
    for (int i = 0; i < 4; ++i) {
        int gr0 = bm + 64 * wr + 16 * i + quad * 4;
#pragma unroll
        for (int j = 0; j < 4; ++j) {
            int gc = bn + 64 * wc + 16 * j + l16;
            float bv = bias ? bias[gc] : 0.0f;
#pragma unroll
            for (int r = 0; r < 4; ++r) {
                int row = gr0 + r;
                if (row >= M) continue;
                float v = acc[i][j][r] + bv;
                if (res) v = s * v + om * (float)res[(long)row * ldc + gc];
                if (Cf) Cf[(long)row * ldc + gc] = v;
                if (Ch) Ch[(long)row * ldc + gc] = (_Float16)v;
                if (bn_accum) { cs[j] += v; cq[j] += v * v; }
            }
        }
    }
    if (bn_accum) {
        // LDS reduce: 8 slots (wr*4+quad) per local column, overlay on As/Bs
        float* redS = (float*)&As[0][0];  // 128*8 floats = 4KB (<=8KB)
        float* redQ = (float*)&Bs[0][0];
        int slot = wr * 4 + quad;
#pragma unroll
        for (int j = 0; j < 4; ++j) {
            int cl = 64 * wc + 16 * j + l16;
            redS[cl * 8 + slot] = cs[j];
            redQ[cl * 8 + slot] = cq[j];
        }
        __syncthreads();
        if (tid < 128) {
            float ssum = 0.f, qsum = 0.f;
#pragma unroll
            for (int t = 0; t < 8; ++t) {
                ssum += redS[tid * 8 + t];
                qsum += redQ[tid * 8 + t];
            }
            atomicAdd(&bn_accum[bn + tid], ssum);
            atomicAdd(&bn_accum[256 + bn + tid], qsum);
        }
    }
}

// ---------------- attention: compact kv table ([K|V] 1024B rows, no q pollution);
// one wave per node, 32-lane halves split edges, shfl_xor(32) state merge;
// fdot2, deferred-max rescale, fused GELU ----------------
template <int H>
__global__ __launch_bounds__(256) void attn_f16kv_kernel(
    const _Float16* __restrict__ qbase,                 // [n][256] f16
    const _Float16* __restrict__ kv,                    // [n][512] f16 = [K|V]
    const float* __restrict__ p_rel,
    const int* __restrict__ row_start, const int* __restrict__ csr_src,
    _Float16* __restrict__ agg, int n)
{
    constexpr int D = 256 / H;
    constexpr int GL = D / 8;  // lanes per head group (8 ch per lane)
    int node = blockIdx.x * 4 + (threadIdx.x >> 6);  // one wave per node
    int lane = threadIdx.x & 63;
    int half = lane >> 5;     // edge-list half
    int l32 = lane & 31;      // channel lane within half
    if (node >= n) return;
    const int head = l32 / GL;
    const float scale = p_rel[head] * rsqrtf((float)D);
    const int ch = l32 * 8;  // == head*D + (l32%GL)*8 for both H=1,4
    f16x8 qv = *(const f16x8*)(qbase + (long)node * 256 + ch);
    f16x2 qp[4];
#pragma unroll
    for (int j = 0; j < 4; ++j) { qp[j][0] = qv[2 * j]; qp[j][1] = qv[2 * j + 1]; }

    const _Float16* kpc = kv + ch;         // K channels at row+[0,256)
    const _Float16* vpc = kv + 256 + ch;   // V channels at row+[256,512)
    int e0all = row_start[node], e1all = row_start[node + 1];
    int c0 = (e1all - e0all + 1) >> 1;      // first-half count (ceil)
    int e0 = half ? (e0all + c0) : e0all;
    int e1 = half ? e1all : (e0all + c0);

    float m = -1e30f, lsum = 0.0f;
    float a[8] = {};

    int e = e0;
    for (; e + 1 < e1; e += 2) {
        int s0 = csr_src[e], s1 = csr_src[e + 1];
        f16x8 k0 = *(const f16x8*)(kpc + (long)s0 * 512);
        f16x8 k1 = *(const f16x8*)(kpc + (long)s1 * 512);
        f16x8 v0 = *(const f16x8*)(vpc + (long)s0 * 512);
        f16x8 v1 = *(const f16x8*)(vpc + (long)s1 * 512);
        float d0 = 0.0f, d1 = 0.0f;
#pragma unroll
        for (int j = 0; j < 4; ++j) {
            f16x2 k0p = {k0[2 * j], k0[2 * j + 1]};
            f16x2 k1p = {k1[2 * j], k1[2 * j + 1]};
            d0 = __builtin_amdgcn_fdot2(qp[j], k0p, d0, false);
            d1 = __builtin_amdgcn_fdot2(qp[j], k1p, d1, false);
        }
#pragma unroll
        for (int off = 1; off < GL; off <<= 1) {
            d0 += __shfl_xor(d0, off);
            d1 += __shfl_xor(d1, off);
        }
        float al0 = d0 * scale, al1 = d1 * scale;
        float mx = fmaxf(al0, al1);
        float diff = mx - m;
        if (__builtin_expect(diff > 8.0f, 0)) {  // deferred-max rescale (rare)
            float corr = __expf(-diff);
            lsum *= corr;
#pragma unroll
            for (int j = 0; j < 8; ++j) a[j] *= corr;
            m = mx;
        }
        float w0 = __expf(al0 - m), w1 = __expf(al1 - m);
        lsum += w0 + w1;
#pragma unroll
        for (int j = 0; j < 8; ++j)
            a[j] += w0 * (float)v0[j] + w1 * (float)v1[j];
    }
    if (e < e1) {
        int s0 = csr_src[e];
        f16x8 k0 = *(const f16x8*)(kpc + (long)s0 * 512);
        f16x8 v0 = *(const f16x8*)(vpc + (long)s0 * 512);
        float d0 = 0.0f;
#pragma unroll
        for (int j = 0; j < 4; ++j) {
            f16x2 k0p = {k0[2 * j], k0[2 * j + 1]};
            d0 = __builtin_amdgcn_fdot2(qp[j], k0p, d0, false);
        }
#pragma unroll
        for (int off = 1; off < GL; off <<= 1) d0 += __shfl_xor(d0, off);
        float al0 = d0 * scale;
        float diff = al0 - m;
        if (__builtin_expect(diff > 8.0f, 0)) {
            float corr = __expf(-diff);
            lsum *= corr;
#pragma unroll
            for (int j = 0; j < 8; ++j) a[j] *= corr;
            m = al0;
        }
        float w0 = __expf(al0 - m);
        lsum += w0;
#pragma unroll
        for (int j = 0; j < 8; ++j) a[j] += w0 * (float)v0[j];
    }

    // merge the two halves' online-softmax states (cross-32 shuffles)
    float m_o = __shfl_xor(m, 32);
    float ls_o = __shfl_xor(lsum, 32);
    float mm = fmaxf(m, m_o);
    float wsf = __expf(m - mm), wo = __expf(m_o - mm);
    lsum = lsum * wsf + ls_o * wo;
#pragma unroll
    for (int j = 0; j < 8; ++j) {
        float a_o = __shfl_xor(a[j], 32);
        a[j] = a[j] * wsf + a_o * wo;
    }

    if (half == 0) {
        float inv = 1.0f / (lsum + 1e-16f);
        f16x8 o;
#pragma unroll
        for (int j = 0; j < 8; ++j) {
            float v = a[j] * inv;
            v = 0.5f * v * (1.0f + erff(v * 0.70710678118654752f));
            o[j] = (_Float16)v;
        }
        *(f16x8*)(agg + (long)node * 256 + ch) = o;
    }
}

// ---------------- BatchNorm apply (f16 in -> f16 out, stats fused in out1) ----
__global__ void bn_apply_kernel(const _Float16* __restrict__ hin, _Float16* __restrict__ hbn,
                                const float* __restrict__ stats,
                                const float* __restrict__ gamma, const float* __restrict__ beta) {
    long idx = blockIdx.x * (long)blockDim.x + threadIdx.x;  // NN*32 f16x8 groups
    if (idx >= (long)NN * 32) return;
    int cg = (int)(idx & 31) * 8;
    f16x8 hv = ((const f16x8*)hin)[idx];
    const float invn = 1.0f / 30000.0f;
    f16x8 o;
#pragma unroll
    for (int r = 0; r < 8; ++r) {
        int c = cg + r;
        float mu = stats[c] * invn;
        float var = stats[256 + c] * invn - mu * mu;
        float v = ((float)hv[r] - mu) * rsqrtf(var + 1e-5f) * gamma[c] + beta[c];
        o[r] = (_Float16)fmaxf(v, 0.0f);
    }
    ((f16x8*)hbn)[idx] = o;
}

// ---------------- launch ----------------
extern "C" void kernel_launch(void* const* d_in, const int* in_sizes, int n_in,
                              void* d_out, int out_size, void* d_ws, size_t ws_size,
                              hipStream_t stream) {
    const float* x       = (const float*)d_in[0];
    const int*   ei      = (const int*)d_in[1];
    const float* w_kqv1  = (const float*)d_in[2];
    const float* b_kqv1  = (const float*)d_in[3];
    const float* k_rel1  = (const float*)d_in[4];
    const float* v_rel1  = (const float*)d_in[5];
    const float* p_rel1  = (const float*)d_in[6];
    const float* w_out1  = (const float*)d_in[7];
    const float* b_out1  = (const float*)d_in[8];
    const float* bn_gamma = (const float*)d_in[10];
    const float* bn_beta  = (const float*)d_in[11];
    const float* w_kqv2  = (const float*)d_in[12];
    const float* b_kqv2  = (const float*)d_in[13];
    const float* k_rel2  = (const float*)d_in[14];
    const float* v_rel2  = (const float*)d_in[15];
    const float* p_rel2  = (const float*)d_in[16];
    const float* w_out2  = (const float*)d_in[17];
    const float* b_out2  = (const float*)d_in[18];
    const float* skip2   = (const float*)d_in[19];
    float* out = (float*)d_out;

    char* p = (char*)d_ws;
    auto alloc = [&](size_t bytes) -> void* {
        void* r = (void*)p;
        p += (bytes + 255) & ~(size_t)255;
        return r;
    };
    _Float16* x_h   = (_Float16*)alloc((size_t)NN * 512 * 2);   // 30.72 MB
    _Float16* kv_h  = (_Float16*)alloc((size_t)NN * 512 * 2);   // 30.72 (compact [K|V])
    _Float16* q_h   = (_Float16*)alloc((size_t)NN * 256 * 2);   // 15.36
    _Float16* agg_h = (_Float16*)alloc((size_t)NN * 256 * 2);   // 15.36
    _Float16* h16   = (_Float16*)alloc((size_t)NN * 256 * 2);   // 15.36 (pre-BN out1)
    _Float16* hbn_h = (_Float16*)alloc((size_t)NN * 256 * 2);   // 15.36 (post-BN/ReLU)
    _Float16* w1T    = (_Float16*)alloc((size_t)768 * 512 * 2); // rows [K|V|Q]
    _Float16* wout1T = (_Float16*)alloc((size_t)256 * 256 * 2);
    _Float16* w2T    = (_Float16*)alloc((size_t)768 * 256 * 2); // rows [K|V|Q]
    _Float16* wout2T = (_Float16*)alloc((size_t)256 * 256 * 2);
    float* bf1       = (float*)alloc(768 * 4);   // [K|V|Q] order
    float* bf2       = (float*)alloc(768 * 4);
    int*   deg       = (int*)alloc((size_t)NN * 4);
    int*   row_start = (int*)alloc((size_t)(NN + 1) * 4);
    int*   pos       = (int*)alloc((size_t)NN * 4);
    int*   csr_src   = (int*)alloc((size_t)NE * 4);
    float* bnstats   = (float*)alloc(512 * 4);   // [256 sums | 256 sqsums]

    const int* esrc = ei;
    const int* edst = ei + NE;

    // ---- conversions + weight folds ----
    cvt_f32_f16_kernel<<<(NN * 512 / 8 + 255) / 256, 256, 0, stream>>>(x, x_h, (long)NN * 512 / 8);
    foldw1_kernel<<<dim3(2, 768), 256, 0, stream>>>(w_kqv1, k_rel1, v_rel1, w1T);
    foldb1_kernel<<<3, 256, 0, stream>>>(b_kqv1, k_rel1, v_rel1, bf1);
    tcvt_kernel<<<dim3(1, 256), 256, 0, stream>>>(w_out1, wout1T, 256, 256);
    foldw2_kernel<<<dim3(1, 768), 256, 0, stream>>>(w_kqv2, k_rel2, v_rel2, w2T);
    foldb2_kernel<<<3, 256, 0, stream>>>(b_kqv2, k_rel2, v_rel2, bf2);
    tcvt_kernel<<<dim3(1, 256), 256, 0, stream>>>(w_out2, wout2T, 256, 256);

    // ---- CSR build ----
    zero_int_kernel<<<(NN + 255) / 256, 256, 0, stream>>>(deg, NN);
    deg_kernel<<<(NE + 255) / 256, 256, 0, stream>>>(edst, deg, NE);
    scan_kernel<<<1, 1024, 0, stream>>>(deg, row_start, pos, NN);
    fill_kernel<<<(NE + 255) / 256, 256, 0, stream>>>(esrc, edst, pos, csr_src, NE);

    const int MB = (NN + 127) / 128;

    // ---- layer 1: kv GEMM (N=512 -> kv_h) + q GEMM (N=256 -> q_h) ----
    mfma_gemm_kernel<<<dim3(4, MB), 256, 0, stream>>>(
        x_h, 512, w1T, nullptr, kv_h, 512, NN, 512, 512, bf1, nullptr, nullptr, nullptr);
    mfma_gemm_kernel<<<dim3(2, MB), 256, 0, stream>>>(
        x_h, 512, w1T + (size_t)512 * 512, nullptr, q_h, 256, NN, 256, 512, bf1 + 512,
        nullptr, nullptr, nullptr);
    attn_f16kv_kernel<4><<<(NN + 3) / 4, 256, 0, stream>>>(
        q_h, kv_h, p_rel1, row_start, csr_src, agg_h, NN);

    // out1: f16 out + fused BN column stats
    zero_float_kernel<<<2, 256, 0, stream>>>(bnstats, 512);
    mfma_gemm_kernel<<<dim3(2, MB), 256, 0, stream>>>(
        agg_h, 256, wout1T, nullptr, h16, 256, NN, 256, 256, b_out1, nullptr, nullptr, bnstats);

    // ---- BatchNorm apply + ReLU (f16 -> f16) ----
    bn_apply_kernel<<<(NN * 32 + 255) / 256, 256, 0, stream>>>(h16, hbn_h, bnstats, bn_gamma, bn_beta);

    // ---- layer 2 ----
    mfma_gemm_kernel<<<dim3(4, MB), 256, 0, stream>>>(
        hbn_h, 256, w2T, nullptr, kv_h, 512, NN, 512, 256, bf2, nullptr, nullptr, nullptr);
    mfma_gemm_kernel<<<dim3(2, MB), 256, 0, stream>>>(
        hbn_h, 256, w2T + (size_t)512 * 256, nullptr, q_h, 256, NN, 256, 256, bf2 + 512,
        nullptr, nullptr, nullptr);
    attn_f16kv_kernel<1><<<(NN + 3) / 4, 256, 0, stream>>>(
        q_h, kv_h, p_rel2, row_start, csr_src, agg_h, NN);
    // out2 + skip (residual = post-BN/ReLU hbn, f16)
    mfma_gemm_kernel<<<dim3(2, MB), 256, 0, stream>>>(
        agg_h, 256, wout2T, out, nullptr, 256, NN, 256, 256, b_out2, hbn_h, skip2, nullptr);
}

// Round 9
// 576.775 us; speedup vs baseline: 1.0694x; 1.0469x over previous
//
#include <hip/hip_runtime.h>
#include <math.h>

#define NN 30000
#define NE 480000

typedef _Float16 f16x8 __attribute__((ext_vector_type(8)));
typedef _Float16 f16x4 __attribute__((ext_vector_type(4)));
typedef _Float16 f16x2 __attribute__((ext_vector_type(2)));
typedef float f32x4 __attribute__((ext_vector_type(4)));

// async global->LDS, 16B per lane, wave-uniform LDS base + lane*16
#define GLOAD_LDS16(gp, lp)                                        \
    __builtin_amdgcn_global_load_lds(                              \
        (const __attribute__((address_space(1))) void*)(gp),       \
        (__attribute__((address_space(3))) void*)(lp), 16, 0, 0)

// ---------------- mega prep kernel: all independent prep in ONE dispatch ----
// jobs (by blockIdx.x range, 256 threads each):
//  A [0,7500)        cvt x f32->f16                  (NN*512/8 groups)
//  B [7500,9036)     foldw1: W1@BD -> w1T [768][512] ([K|Q|V] rows)
//  C [9036,9039)     foldb1 -> bf1[768]
//  D [9039,9295)     tcvt w_out1 -> wout1T
//  E [9295,10063)    foldw2 -> w2T [768][256]
//  F [10063,10066)   foldb2 -> bf2[768]
//  G [10066,10322)   tcvt w_out2 -> wout2T
//  H [10322,10440)   zero deg[NN]
//  I [10440,10442)   zero bnstats[512]
#define PREP_BLOCKS 10442
__global__ __launch_bounds__(256) void prep_kernel(
    const float* __restrict__ x, _Float16* __restrict__ x_h,
    const float* __restrict__ w_kqv1, const float* __restrict__ krel,
    const float* __restrict__ vrel, _Float16* __restrict__ w1T,
    const float* __restrict__ b_kqv1, float* __restrict__ bf1,
    const float* __restrict__ w_out1, _Float16* __restrict__ wout1T,
    const float* __restrict__ w_kqv2, const float* __restrict__ krel2,
    const float* __restrict__ vrel2, _Float16* __restrict__ w2T,
    const float* __restrict__ b_kqv2, float* __restrict__ bf2,
    const float* __restrict__ w_out2, _Float16* __restrict__ wout2T,
    int* __restrict__ deg, float* __restrict__ bnstats)
{
    const int bid = blockIdx.x, tid = threadIdx.x;
    if (bid < 7500) {                       // A: cvt x -> f16 (8 elems/thread)
        long i = (long)bid * 256 + tid;     // < 1,920,000 exactly
        float4 a = ((const float4*)x)[2 * i];
        float4 b = ((const float4*)x)[2 * i + 1];
        f16x8 o = {(_Float16)a.x, (_Float16)a.y, (_Float16)a.z, (_Float16)a.w,
                   (_Float16)b.x, (_Float16)b.y, (_Float16)b.z, (_Float16)b.w};
        ((f16x8*)x_h)[i] = o;
    } else if (bid < 9036) {                // B: foldw1 ([K|Q|V] col order)
        int rel = bid - 7500;
        int n = rel >> 1;                   // 0..767
        int k = (rel & 1) * 256 + tid;      // 0..511
        float acc;
        if (n < 256) {
            int h = n >> 6, e = n & 63;
            const float* wr = w_kqv1 + (long)k * 768 + h * 64;
            const float* kr = krel + h * 4096 + e;
            acc = 0.f;
            for (int d = 0; d < 64; ++d) acc += wr[d] * kr[(long)d * 64];
        } else if (n < 512) {
            acc = w_kqv1[(long)k * 768 + n];
        } else {
            int m = n - 512, h = m >> 6, e = m & 63;
            const float* wr = w_kqv1 + (long)k * 768 + 512 + h * 64;
            const float* vr = vrel + h * 4096 + e;
            acc = 0.f;
            for (int d = 0; d < 64; ++d) acc += wr[d] * vr[(long)d * 64];
        }
        w1T[(long)n * 512 + k] = (_Float16)acc;
    } else if (bid < 9039) {                // C: foldb1
        int n = (bid - 9036) * 256 + tid;   // < 768
        float acc;
        if (n < 256) {
            int h = n >> 6, e = n & 63;
            acc = 0.f;
            for (int d = 0; d < 64; ++d) acc += b_kqv1[h * 64 + d] * krel[h * 4096 + d * 64 + e];
        } else if (n < 512) {
            acc = b_kqv1[n];
        } else {
            int m = n - 512, h = m >> 6, e = m & 63;
            acc = 0.f;
            for (int d = 0; d < 64; ++d) acc += b_kqv1[512 + h * 64 + d] * vrel[h * 4096 + d * 64 + e];
        }
        bf1[n] = acc;
    } else if (bid < 9295) {                // D: tcvt w_out1 (256x256)
        int k = bid - 9039;                 // 0..255
        int n = tid;
        wout1T[(long)n * 256 + k] = (_Float16)w_out1[(long)k * 256 + n];
    } else if (bid < 10063) {               // E: foldw2
        int n = bid - 9295;                 // 0..767
        int k = tid;                        // 0..255
        float acc;
        if (n < 256) {
            const float* wr = w_kqv2 + (long)k * 768;
            const float* kr = krel2 + n;
            acc = 0.f;
            for (int d = 0; d < 256; ++d) acc += wr[d] * kr[(long)d * 256];
        } else if (n < 512) {
            acc = w_kqv2[(long)k * 768 + n];
        } else {
            const float* wr = w_kqv2 + (long)k * 768 + 512;
            const float* vr = vrel2 + (n - 512);
            acc = 0.f;
            for (int d = 0; d < 256; ++d) acc += wr[d] * vr[(long)d * 256];
        }
        w2T[(long)n * 256 + k] = (_Float16)acc;
    } else if (bid < 10066) {               // F: foldb2
        int n = (bid - 10063) * 256 + tid;  // < 768
        float acc;
        if (n < 256) {
            acc = 0.f;
            for (int d = 0; d < 256; ++d) acc += b_kqv2[d] * krel2[(long)d * 256 + n];
        } else if (n < 512) {
            acc = b_kqv2[n];
        } else {
            acc = 0.f;
            for (int d = 0; d < 256; ++d) acc += b_kqv2[512 + d] * vrel2[(long)d * 256 + (n - 512)];
        }
        bf2[n] = acc;
    } else if (bid < 10322) {               // G: tcvt w_out2
        int k = bid - 10066;
        int n = tid;
        wout2T[(long)n * 256 + k] = (_Float16)w_out2[(long)k * 256 + n];
    } else if (bid < 10440) {               // H: zero deg
        int i = (bid - 10322) * 256 + tid;
        if (i < NN) deg[i] = 0;
    } else {                                // I: zero bnstats
        int i = (bid - 10440) * 256 + tid;
        if (i < 512) bnstats[i] = 0.0f;
    }
}

// ---------------- CSR build ----------------
__global__ void deg_kernel(const int* __restrict__ dst, int* __restrict__ deg, int e) {
    int i = blockIdx.x * blockDim.x + threadIdx.x;
    if (i < e) atomicAdd(&deg[dst[i]], 1);
}

// single-tile scan: each thread owns 32 contiguous elements (int4 loads),
// then one 1024-wide Hillis-Steele pass
__global__ __launch_bounds__(1024) void scan_kernel(
    const int* __restrict__ deg, int* __restrict__ row_start,
    int* __restrict__ pos, int n)
{
    __shared__ int smem[1024];
    const int t = threadIdx.x;
    const int base = t * 32;  // 1024*32 = 32768 >= 30000
    int loc[32];
    int s = 0;
#pragma unroll
    for (int g = 0; g < 8; ++g) {
        int idx = base + g * 4;
        int4 d4;
        if (idx + 3 < n) {
            d4 = *(const int4*)(deg + idx);
        } else {
            d4.x = (idx + 0 < n) ? deg[idx + 0] : 0;
            d4.y = (idx + 1 < n) ? deg[idx + 1] : 0;
            d4.z = (idx + 2 < n) ? deg[idx + 2] : 0;
            d4.w = (idx + 3 < n) ? deg[idx + 3] : 0;
        }
        loc[g * 4 + 0] = s; s += d4.x;
        loc[g * 4 + 1] = s; s += d4.y;
        loc[g * 4 + 2] = s; s += d4.z;
        loc[g * 4 + 3] = s; s += d4.w;
    }
    smem[t] = s;
    __syncthreads();
    for (int off = 1; off < 1024; off <<= 1) {
        int tv = 0;
        if (t >= off) tv = smem[t - off];
        __syncthreads();
        smem[t] += tv;
        __syncthreads();
    }
    const int excl = smem[t] - s;
#pragma unroll
    for (int g = 0; g < 32; ++g) {
        int idx = base + g;
        if (idx < n) {
            int r = excl + loc[g];
            row_start[idx] = r;
            pos[idx] = r;
        }
    }
    if (t == 1023) row_start[n] = smem[1023];
}

__global__ void fill_kernel(const int* __restrict__ src, const int* __restrict__ dst,
                            int* __restrict__ pos, int* __restrict__ csr_src, int e) {
    int i = blockIdx.x * blockDim.x + threadIdx.x;
    if (i < e) {
        int p = atomicAdd(&pos[dst[i]], 1);
        csr_src[p] = src[i];
    }
}

// ---------------- fp16 MFMA GEMM: global_load_lds staging, linear [128][32] LDS,
// optional f16 residual blend + optional fused BN column-stats epilogue
// (verified round-6 configuration) ----------------
__global__ __launch_bounds__(256) void mfma_gemm_kernel(
    const _Float16* __restrict__ A, int lda,
    const _Float16* __restrict__ BT,
    float* __restrict__ Cf,
    _Float16* __restrict__ Ch,
    int ldc, int M, int N, int K,
    const float* __restrict__ bias,
    const _Float16* __restrict__ res,   // f16 residual (skip blend), ld = ldc
    const float* __restrict__ skip,
    float* __restrict__ bn_accum)       // [512]: col sums then col sqsums
{
    __shared__ __align__(16) _Float16 As[128][32];
    __shared__ __align__(16) _Float16 Bs[128][32];
    const int tid = threadIdx.x;
    const int bm = blockIdx.y * 128, bn = blockIdx.x * 128;
    const int wave = tid >> 6, lane = tid & 63;
    const int wr = wave >> 1, wc = wave & 1;
    const int l16 = lane & 15, quad = lane >> 4;

    // staging chunk map: chunk c (0..511) of 16B -> LDS byte c*16 -> row=c>>2, col8=(c&3)*8
    const int r0 = tid >> 2, kc0 = (tid & 3) * 8;
    const int r1 = r0 + 64;
    int gra0 = bm + r0; if (gra0 >= M) gra0 = M - 1;  // DMA has no predication;
    int gra1 = bm + r1; if (gra1 >= M) gra1 = M - 1;  // C-store is row-guarded
    const _Float16* a0 = A + (long)gra0 * lda + kc0;
    const _Float16* a1 = A + (long)gra1 * lda + kc0;
    const _Float16* b0 = BT + (long)(bn + r0) * K + kc0;
    const _Float16* b1 = BT + (long)(bn + r1) * K + kc0;

    auto ldsA = (__attribute__((address_space(3))) char*)&As[0][0];
    auto ldsB = (__attribute__((address_space(3))) char*)&Bs[0][0];
    const int wb = wave * 1024;  // wave-uniform LDS base (lane*16 added by HW)

    f32x4 acc[4][4] = {};

    for (int k0 = 0; k0 < K; k0 += 32) {
        GLOAD_LDS16(a0 + k0, ldsA + wb);
        GLOAD_LDS16(a1 + k0, ldsA + 4096 + wb);
        GLOAD_LDS16(b0 + k0, ldsB + wb);
        GLOAD_LDS16(b1 + k0, ldsB + 4096 + wb);
        __syncthreads();
        f16x8 af[4], bf[4];
#pragma unroll
        for (int i = 0; i < 4; ++i)
            af[i] = *(const f16x8*)&As[64 * wr + 16 * i + l16][quad * 8];
#pragma unroll
        for (int j = 0; j < 4; ++j)
            bf[j] = *(const f16x8*)&Bs[64 * wc + 16 * j + l16][quad * 8];
#pragma unroll
        for (int i = 0; i < 4; ++i)
#pragma unroll
            for (int j = 0; j < 4; ++j)
                acc[i][j] = __builtin_amdgcn_mfma_f32_16x16x32_f16(af[i], bf[j], acc[i][j], 0, 0, 0);
        __syncthreads();
    }

    float s = 1.0f, om = 0.0f;
    if (skip) {
        float sv = 1.0f / (1.0f + __expf(-skip[0]));
        s = sv; om = 1.0f - sv;
    }
    float cs[4] = {}, cq[4] = {};
#pragma unroll
    for (int i = 0; i < 4; ++i) {
        int gr0 = bm + 64 * wr + 16 * i + quad * 4;
#pragma unroll
        for (int j = 0; j < 4; ++j) {
            int gc = bn + 64 * wc + 16 * j + l16;
            float bv = bias ? bias[gc] : 0.0f;
#pragma unroll
            for (int r = 0; r < 4; ++r) {
                int row = gr0 + r;
                if (row >= M) continue;
                float v = acc[i][j][r] + bv;
                if (res) v = s * v + om * (float)res[(long)row * ldc + gc];
                if (Cf) Cf[(long)row * ldc + gc] = v;
                if (Ch) Ch[(long)row * ldc + gc] = (_Float16)v;
                if (bn_accum) { cs[j] += v; cq[j] += v * v; }
            }
        }
    }
    if (bn_accum) {
        // LDS reduce: 8 slots (wr*4+quad) per local column, overlay on As/Bs
        float* redS = (float*)&As[0][0];  // 128*8 floats = 4KB (<=8KB)
        float* redQ = (float*)&Bs[0][0];
        int slot = wr * 4 + quad;
#pragma unroll
        for (int j = 0; j < 4; ++j) {
            int cl = 64 * wc + 16 * j + l16;
            redS[cl * 8 + slot] = cs[j];
            redQ[cl * 8 + slot] = cq[j];
        }
        __syncthreads();
        if (tid < 128) {
            float ssum = 0.f, qsum = 0.f;
#pragma unroll
            for (int t = 0; t < 8; ++t) {
                ssum += redS[tid * 8 + t];
                qsum += redQ[tid * 8 + t];
            }
            atomicAdd(&bn_accum[bn + tid], ssum);
            atomicAdd(&bn_accum[256 + bn + tid], qsum);
        }
    }
}

// ---------------- attention (verified round-6): one wave per node; 32-lane halves
// split the edge list, merge online-softmax states via shfl_xor(32);
// f16 K/V strided gathers, fdot2, deferred-max rescale, fused GELU ----------------
template <int H>
__global__ __launch_bounds__(256) void attn_f16kv_kernel(
    const _Float16* __restrict__ qbase, int ldq,
    const _Float16* __restrict__ kp, const _Float16* __restrict__ vp, int ldkv,
    const float* __restrict__ p_rel,
    const int* __restrict__ row_start, const int* __restrict__ csr_src,
    _Float16* __restrict__ agg, int n)
{
    constexpr int D = 256 / H;
    constexpr int GL = D / 8;  // lanes per head group (8 ch per lane)
    int node = blockIdx.x * 4 + (threadIdx.x >> 6);  // one wave per node
    int lane = threadIdx.x & 63;
    int half = lane >> 5;     // edge-list half
    int l32 = lane & 31;      // channel lane within half
    if (node >= n) return;
    const int head = l32 / GL;
    const float scale = p_rel[head] * rsqrtf((float)D);
    const int ch = l32 * 8;  // == head*D + (l32%GL)*8 for both H=1,4
    f16x8 qv = *(const f16x8*)(qbase + (long)node * ldq + ch);
    f16x2 qp[4];
#pragma unroll
    for (int j = 0; j < 4; ++j) { qp[j][0] = qv[2 * j]; qp[j][1] = qv[2 * j + 1]; }

    const _Float16* kpc = kp + ch;
    const _Float16* vpc = vp + ch;
    int e0all = row_start[node], e1all = row_start[node + 1];
    int c0 = (e1all - e0all + 1) >> 1;      // first-half count (ceil)
    int e0 = half ? (e0all + c0) : e0all;
    int e1 = half ? e1all : (e0all + c0);

    float m = -1e30f, lsum = 0.0f;
    float a[8] = {};

    int e = e0;
    for (; e + 1 < e1; e += 2) {
        int s0 = csr_src[e], s1 = csr_src[e + 1];
        f16x8 k0 = *(const f16x8*)(kpc + (long)s0 * ldkv);
        f16x8 k1 = *(const f16x8*)(kpc + (long)s1 * ldkv);
        f16x8 v0 = *(const f16x8*)(vpc + (long)s0 * ldkv);
        f16x8 v1 = *(const f16x8*)(vpc + (long)s1 * ldkv);
        float d0 = 0.0f, d1 = 0.0f;
#pragma unroll
        for (int j = 0; j < 4; ++j) {
            f16x2 k0p = {k0[2 * j], k0[2 * j + 1]};
            f16x2 k1p = {k1[2 * j], k1[2 * j + 1]};
            d0 = __builtin_amdgcn_fdot2(qp[j], k0p, d0, false);
            d1 = __builtin_amdgcn_fdot2(qp[j], k1p, d1, false);
        }
#pragma unroll
        for (int off = 1; off < GL; off <<= 1) {
            d0 += __shfl_xor(d0, off);
            d1 += __shfl_xor(d1, off);
        }
        float al0 = d0 * scale, al1 = d1 * scale;
        float mx = fmaxf(al0, al1);
        float diff = mx - m;
        if (__builtin_expect(diff > 8.0f, 0)) {  // deferred-max rescale (rare)
            float corr = __expf(-diff);
            lsum *= corr;
#pragma unroll
            for (int j = 0; j < 8; ++j) a[j] *= corr;
            m = mx;
        }
        float w0 = __expf(al0 - m), w1 = __expf(al1 - m);
        lsum += w0 + w1;
#pragma unroll
        for (int j = 0; j < 8; ++j)
            a[j] += w0 * (float)v0[j] + w1 * (float)v1[j];
    }
    if (e < e1) {
        int s0 = csr_src[e];
        f16x8 k0 = *(const f16x8*)(kpc + (long)s0 * ldkv);
        f16x8 v0 = *(const f16x8*)(vpc + (long)s0 * ldkv);
        float d0 = 0.0f;
#pragma unroll
        for (int j = 0; j < 4; ++j) {
            f16x2 k0p = {k0[2 * j], k0[2 * j + 1]};
            d0 = __builtin_amdgcn_fdot2(qp[j], k0p, d0, false);
        }
#pragma unroll
        for (int off = 1; off < GL; off <<= 1) d0 += __shfl_xor(d0, off);
        float al0 = d0 * scale;
        float diff = al0 - m;
        if (__builtin_expect(diff > 8.0f, 0)) {
            float corr = __expf(-diff);
            lsum *= corr;
#pragma unroll
            for (int j = 0; j < 8; ++j) a[j] *= corr;
            m = al0;
        }
        float w0 = __expf(al0 - m);
        lsum += w0;
#pragma unroll
        for (int j = 0; j < 8; ++j) a[j] += w0 * (float)v0[j];
    }

    // merge the two halves' online-softmax states (cross-32 shuffles)
    float m_o = __shfl_xor(m, 32);
    float ls_o = __shfl_xor(lsum, 32);
    float mm = fmaxf(m, m_o);
    float wsf = __expf(m - mm), wo = __expf(m_o - mm);
    lsum = lsum * wsf + ls_o * wo;
#pragma unroll
    for (int j = 0; j < 8; ++j) {
        float a_o = __shfl_xor(a[j], 32);
        a[j] = a[j] * wsf + a_o * wo;
    }

    if (half == 0) {
        float inv = 1.0f / (lsum + 1e-16f);
        f16x8 o;
#pragma unroll
        for (int j = 0; j < 8; ++j) {
            float v = a[j] * inv;
            v = 0.5f * v * (1.0f + erff(v * 0.70710678118654752f));
            o[j] = (_Float16)v;
        }
        *(f16x8*)(agg + (long)node * 256 + ch) = o;
    }
}

// ---------------- BatchNorm apply (f16 in -> f16 out, stats fused in out1) ----
__global__ void bn_apply_kernel(const _Float16* __restrict__ hin, _Float16* __restrict__ hbn,
                                const float* __restrict__ stats,
                                const float* __restrict__ gamma, const float* __restrict__ beta) {
    long idx = blockIdx.x * (long)blockDim.x + threadIdx.x;  // NN*32 f16x8 groups
    if (idx >= (long)NN * 32) return;
    int cg = (int)(idx & 31) * 8;
    f16x8 hv = ((const f16x8*)hin)[idx];
    const float invn = 1.0f / 30000.0f;
    f16x8 o;
#pragma unroll
    for (int r = 0; r < 8; ++r) {
        int c = cg + r;
        float mu = stats[c] * invn;
        float var = stats[256 + c] * invn - mu * mu;
        float v = ((float)hv[r] - mu) * rsqrtf(var + 1e-5f) * gamma[c] + beta[c];
        o[r] = (_Float16)fmaxf(v, 0.0f);
    }
    ((f16x8*)hbn)[idx] = o;
}

// ---------------- launch (11 dispatches, was 19) ----------------
extern "C" void kernel_launch(void* const* d_in, const int* in_sizes, int n_in,
                              void* d_out, int out_size, void* d_ws, size_t ws_size,
                              hipStream_t stream) {
    const float* x       = (const float*)d_in[0];
    const int*   ei      = (const int*)d_in[1];
    const float* w_kqv1  = (const float*)d_in[2];
    const float* b_kqv1  = (const float*)d_in[3];
    const float* k_rel1  = (const float*)d_in[4];
    const float* v_rel1  = (const float*)d_in[5];
    const float* p_rel1  = (const float*)d_in[6];
    const float* w_out1  = (const float*)d_in[7];
    const float* b_out1  = (const float*)d_in[8];
    const float* bn_gamma = (const float*)d_in[10];
    const float* bn_beta  = (const float*)d_in[11];
    const float* w_kqv2  = (const float*)d_in[12];
    const float* b_kqv2  = (const float*)d_in[13];
    const float* k_rel2  = (const float*)d_in[14];
    const float* v_rel2  = (const float*)d_in[15];
    const float* p_rel2  = (const float*)d_in[16];
    const float* w_out2  = (const float*)d_in[17];
    const float* b_out2  = (const float*)d_in[18];
    const float* skip2   = (const float*)d_in[19];
    float* out = (float*)d_out;

    char* p = (char*)d_ws;
    auto alloc = [&](size_t bytes) -> void* {
        void* r = (void*)p;
        p += (bytes + 255) & ~(size_t)255;
        return r;
    };
    _Float16* x_h   = (_Float16*)alloc((size_t)NN * 512 * 2);   // 30.72 MB
    _Float16* kqv_h = (_Float16*)alloc((size_t)NN * 768 * 2);   // 46.08 (holds kp|q|vp)
    _Float16* agg_h = (_Float16*)alloc((size_t)NN * 256 * 2);   // 15.36
    _Float16* h16   = (_Float16*)alloc((size_t)NN * 256 * 2);   // 15.36 (pre-BN out1)
    _Float16* hbn_h = (_Float16*)alloc((size_t)NN * 256 * 2);   // 15.36 (post-BN/ReLU)
    _Float16* w1T    = (_Float16*)alloc((size_t)768 * 512 * 2);
    _Float16* wout1T = (_Float16*)alloc((size_t)256 * 256 * 2);
    _Float16* w2T    = (_Float16*)alloc((size_t)768 * 256 * 2);
    _Float16* wout2T = (_Float16*)alloc((size_t)256 * 256 * 2);
    float* bf1       = (float*)alloc(768 * 4);
    float* bf2       = (float*)alloc(768 * 4);
    int*   deg       = (int*)alloc((size_t)NN * 4);
    int*   row_start = (int*)alloc((size_t)(NN + 1) * 4);
    int*   pos       = (int*)alloc((size_t)NN * 4);
    int*   csr_src   = (int*)alloc((size_t)NE * 4);
    float* bnstats   = (float*)alloc(512 * 4);   // [256 sums | 256 sqsums]

    const int* esrc = ei;
    const int* edst = ei + NE;

    // ---- 1: all prep (cvt, folds, transposes, zeros) in one dispatch ----
    prep_kernel<<<PREP_BLOCKS, 256, 0, stream>>>(
        x, x_h, w_kqv1, k_rel1, v_rel1, w1T, b_kqv1, bf1, w_out1, wout1T,
        w_kqv2, k_rel2, v_rel2, w2T, b_kqv2, bf2, w_out2, wout2T, deg, bnstats);

    // ---- 2-4: CSR build ----
    deg_kernel<<<(NE + 255) / 256, 256, 0, stream>>>(edst, deg, NE);
    scan_kernel<<<1, 1024, 0, stream>>>(deg, row_start, pos, NN);
    fill_kernel<<<(NE + 255) / 256, 256, 0, stream>>>(esrc, edst, pos, csr_src, NE);

    const int MB = (NN + 127) / 128;

    // ---- 5-7: layer 1 ----
    mfma_gemm_kernel<<<dim3(6, MB), 256, 0, stream>>>(
        x_h, 512, w1T, nullptr, kqv_h, 768, NN, 768, 512, bf1, nullptr, nullptr, nullptr);
    attn_f16kv_kernel<4><<<(NN + 3) / 4, 256, 0, stream>>>(
        kqv_h + 256, 768, kqv_h, kqv_h + 512, 768, p_rel1, row_start, csr_src, agg_h, NN);
    mfma_gemm_kernel<<<dim3(2, MB), 256, 0, stream>>>(
        agg_h, 256, wout1T, nullptr, h16, 256, NN, 256, 256, b_out1, nullptr, nullptr, bnstats);

    // ---- 8: BatchNorm apply + ReLU (f16 -> f16) ----
    bn_apply_kernel<<<(NN * 32 + 255) / 256, 256, 0, stream>>>(h16, hbn_h, bnstats, bn_gamma, bn_beta);

    // ---- 9-11: layer 2 ----
    mfma_gemm_kernel<<<dim3(6, MB), 256, 0, stream>>>(
        hbn_h, 256, w2T, nullptr, kqv_h, 768, NN, 768, 256, bf2, nullptr, nullptr, nullptr);
    attn_f16kv_kernel<1><<<(NN + 3) / 4, 256, 0, stream>>>(
        kqv_h + 256, 768, kqv_h, kqv_h + 512, 768, p_rel2, row_start, csr_src, agg_h, NN);
    mfma_gemm_kernel<<<dim3(2, MB), 256, 0, stream>>>(
        agg_h, 256, wout2T, out, nullptr, 256, NN, 256, 256, b_out2, hbn_h, skip2, nullptr);
}